// Round 11
// baseline (227.864 us; speedup 1.0000x reference)
//
#include <hip/hip_runtime.h>
#include <hip/hip_bf16.h>

#define NHEAD 8
#define DKH 64
#define DMODEL 512
#define SEQ 4096
#define BATCH 2
#define MROWS (BATCH * SEQ)  // 8192

using bf16x8 = __attribute__((ext_vector_type(8))) short;
using s16x4  = __attribute__((ext_vector_type(4))) short;
using f32x4  = __attribute__((ext_vector_type(4))) float;
using f32x16 = __attribute__((ext_vector_type(16))) float;

__device__ __forceinline__ float b2f(unsigned short u) {
    union { unsigned short u; __hip_bfloat16 h; } c; c.u = u; return __bfloat162float(c.h);
}
// round-half-up f32->bf16: 2 VALU ops, max rel err 2^-9.
__device__ __forceinline__ short rhu(float x) {
    union { float f; unsigned u; } c; c.f = x;
    return (short)((c.u + 0x8000u) >> 16);
}

// HW convert+pack: two f32 -> one dword of 2 bf16 (RNE). 1 VALU instr.
__device__ __forceinline__ unsigned cvtpk(float lo, float hi) {
    unsigned r;
    asm("v_cvt_pk_bf16_f32 %0, %1, %2" : "=v"(r) : "v"(lo), "v"(hi));
    return r;
}

// Bare v_exp_f32 (2^x). Fixed-max softmax keeps inputs in normal range.
#if __has_builtin(__builtin_amdgcn_exp2f)
#define EXP2F(x) __builtin_amdgcn_exp2f(x)
#else
#define EXP2F(x) exp2f(x)
#endif

// Direct global->LDS DMA, 16 B/lane. LDS dest must be WAVE-UNIFORM base
// (HW adds lane*16); global src is per-lane (m104/m173).
__device__ __forceinline__ void gload_lds16(const void* g, void* l) {
    __builtin_amdgcn_global_load_lds(
        (const __attribute__((address_space(1))) void*)g,
        (__attribute__((address_space(3))) void*)l,
        16, 0, 0);
}

// ---------------------------------------------------------------------------
// Pre-convert pass: fp32 -> bf16 for q,k,v and all four weight matrices so
// every GEMM operand stages via global_load_lds. Memory-bound (~81 MB moved,
// ~13 us = at BW ceiling). dst: qb | kb | vb | Wqb | Wkb | Wvb | Wob.
// ---------------------------------------------------------------------------
#define QG ((size_t)MROWS * DMODEL / 8)   // 524288 8-elem groups per tensor
#define WG ((size_t)DMODEL * DMODEL / 8)  // 32768 per weight

__global__ __launch_bounds__(256) void convert_kernel(
    const float* __restrict__ q, const float* __restrict__ k, const float* __restrict__ v,
    const float* __restrict__ Wq, const float* __restrict__ Wk,
    const float* __restrict__ Wv, const float* __restrict__ Wo,
    short* __restrict__ dst) {
    const size_t i = (size_t)blockIdx.x * 256 + threadIdx.x;  // 8-elem group
    const float* src;
    size_t off;
    if (i < 3 * QG) {
        size_t s = i / QG;                 // pow2 shift
        off = (i - s * QG) * 8;
        src = (s == 0) ? q : (s == 1) ? k : v;
    } else {
        size_t j = i - 3 * QG;
        size_t s = j / WG;
        off = (j - s * WG) * 8;
        src = (s == 0) ? Wq : (s == 1) ? Wk : (s == 2) ? Wv : Wo;
    }
    float4 a = *(const float4*)(src + off);
    float4 b = *(const float4*)(src + off + 4);
    union { unsigned u[4]; bf16x8 v8; } t;
    t.u[0] = cvtpk(a.x, a.y);
    t.u[1] = cvtpk(a.z, a.w);
    t.u[2] = cvtpk(b.x, b.y);
    t.u[3] = cvtpk(b.z, b.w);
    *(bf16x8*)&dst[i * 8] = t.v8;
}

// ---------------------------------------------------------------------------
// GEMM core — round-3 structure (rest = 136.4/137.3 us, twice reproduced):
// single-buffer width-16 global_load_lds into linear LDS [row][64],
// XOR-swizzled both-sides (rule #21); 2-barrier K-loop (m114 wave TLP does
// the pipelining; dbuf cost ~6 us via occupancy, m132); SCALAR epilogues,
// channel-per-lane orientation (coalesced; swapped wide stores cost ~11 us).
// EPI 0: out[m*512+n] fp32                            [oproj]
// EPI 1: head scatter [b,h,s,dk], bf16                [Q,K proj]
// EPI 2: permuted V^T scatter [b,h,dk,perm(s)], bf16  [V proj]
// ---------------------------------------------------------------------------
template <int EPI, int TM>
__device__ __forceinline__ void gemm_core(const short* __restrict__ A,
                                          const short* __restrict__ W,
                                          const float* __restrict__ bias,
                                          void* __restrict__ out,
                                          int bm, int bn) {
    constexpr int MT = TM / 32;            // 16-row tiles per wave (m dir)
    constexpr int AI = TM / 32;            // lA DMA instrs per wave
    __shared__ __align__(128) short lA[TM * 64];
    __shared__ __align__(128) short lB[128 * 64];

    const int tid  = threadIdx.x;
    const int lane = tid & 63;
    const int w    = tid >> 6;
    const int wr = w >> 1, wc = w & 1;
    const int g = lane >> 4, ln = lane & 15;
    const int l8 = lane >> 3, cb = lane & 7;   // DMA: row-in-group, col-group
    const int sw8 = cb ^ l8;                   // pre-swizzled global k8-group

    const f32x4 zero = {0.f, 0.f, 0.f, 0.f};
    f32x4 acc[MT][4];
    for (int mt = 0; mt < MT; mt++)
        for (int nt = 0; nt < 4; nt++) acc[mt][nt] = zero;

    for (int kb = 0; kb < DMODEL; kb += 64) {
        for (int i = 0; i < AI; i++) {
            const int rb = w * (8 * AI) + i * 8;     // wave-uniform row base
            gload_lds16(&A[(size_t)(bm + rb + l8) * DMODEL + kb + sw8 * 8],
                        &lA[rb * 64]);
        }
        for (int i = 0; i < 4; i++) {
            const int rb = w * 32 + i * 8;
            gload_lds16(&W[(size_t)(bn + rb + l8) * DMODEL + kb + sw8 * 8],
                        &lB[rb * 64]);
        }
        __syncthreads();   // compiler emits vmcnt(0) drain here

        for (int ks = 0; ks < 2; ks++) {
            const int xr = (ks * 4 + g) ^ (ln & 7);  // swizzled 16B slot
            bf16x8 af[MT], bf[4];
            for (int mt = 0; mt < MT; mt++) {
                const int row = wr * 16 * MT + mt * 16 + ln;
                af[mt] = *(const bf16x8*)&lA[row * 64 + xr * 8];
            }
            for (int nt = 0; nt < 4; nt++) {
                const int row = wc * 64 + nt * 16 + ln;
                bf[nt] = *(const bf16x8*)&lB[row * 64 + xr * 8];
            }
            for (int mt = 0; mt < MT; mt++)
                for (int nt = 0; nt < 4; nt++)
                    acc[mt][nt] = __builtin_amdgcn_mfma_f32_16x16x32_bf16(
                        af[mt], bf[nt], acc[mt][nt], 0, 0, 0);
        }
        __syncthreads();
    }

    if (EPI == 2) {
        for (int mt = 0; mt < MT; mt++) {
            for (int r = 0; r < 4; r++) {
                const int m = bm + wr * 16 * MT + mt * 16 + g * 4 + r;  // channel
                const float bz = ((const float*)bias)[m];
                const int hh = m >> 6, dk = m & 63;
                for (int nt = 0; nt < 4; nt++) {
                    const int n = bn + wc * 64 + nt * 16 + ln;          // token
                    const int bb = n >> 12, s = n & 4095;
                    const int sl = s & 127, sh = s & ~127;
                    const int kt = sl >> 5, kk = sl & 31;
                    const int t = kk >> 3, hb = (kk >> 2) & 1, lo = kk & 3;
                    const int kappa = kt * 32 + (t >> 1) * 16 + hb * 8 + (t & 1) * 4 + lo;
                    ((short*)out)[(((size_t)(bb * NHEAD + hh)) * DKH + dk) * SEQ + sh + kappa] =
                        rhu(acc[mt][nt][r] + bz);
                }
            }
        }
    } else {
        for (int nt = 0; nt < 4; nt++) {
            const int n = bn + wc * 64 + nt * 16 + ln;
            const float bz = ((const float*)bias)[n];
            for (int mt = 0; mt < MT; mt++) {
                for (int r = 0; r < 4; r++) {
                    const int m = bm + wr * 16 * MT + mt * 16 + g * 4 + r;
                    const float val = acc[mt][nt][r] + bz;
                    if (EPI == 1) {
                        const int bb = m >> 12, s = m & 4095;
                        const int hh = n >> 6, dk = n & 63;
                        ((short*)out)[(((size_t)(bb * NHEAD + hh)) * SEQ + s) * DKH + dk] =
                            rhu(val);
                    } else {
                        ((float*)out)[(size_t)m * DMODEL + n] = val;
                    }
                }
            }
        }
    }
}

// Merged Q/K/V projections: z=0 Q, z=1 K (EPI1, A=data tokens on M);
// z=2 V^T (EPI2, A=weights channels on M, coords swapped).
__global__ __launch_bounds__(256) void qkv_kernel(
    const short* __restrict__ qb, const short* __restrict__ kb, const short* __restrict__ vb,
    const short* __restrict__ Wqb, const short* __restrict__ Wkb, const short* __restrict__ Wvb,
    const float* __restrict__ bq, const float* __restrict__ bk, const float* __restrict__ bv,
    short* __restrict__ Qh, short* __restrict__ Kh, short* __restrict__ Vt) {
    if (blockIdx.z == 0) {
        gemm_core<1, 128>(qb, Wqb, bq, Qh, blockIdx.x * 128, blockIdx.y * 128);
    } else if (blockIdx.z == 1) {
        gemm_core<1, 128>(kb, Wkb, bk, Kh, blockIdx.x * 128, blockIdx.y * 128);
    } else {
        // vproj operand-swapped: rows = channels (y), cols = tokens (x)
        gemm_core<2, 128>(Wvb, vb, bv, Vt, blockIdx.y * 128, blockIdx.x * 128);
    }
}

// oproj: A = concat (tokens on M, TM=64), W = Wo. 512 blocks, 24 KB LDS.
__global__ __launch_bounds__(256) void oproj_kernel(
    const short* __restrict__ A, const short* __restrict__ W,
    const float* __restrict__ bias, float* __restrict__ out) {
    gemm_core<0, 64>(A, W, bias, out, blockIdx.x * 64, blockIdx.y * 128);
}

// ---------------------------------------------------------------------------
// Flash attention — round-7 verified structure (stage -> sync -> compute ->
// sync, setprio around MFMA clusters). Round 10 change: K/V staging via
// global_load_lds DMA into linear swizzled LDS instead of the reg round-trip
// (8 loads + 8 ds_writes + addr math -> 8 DMA per thread-tile; Common-
// mistake #1, same pattern as gemm_core).
//  lK [128][64] linear; slot-XOR: slot s of row r holds k-group s ^ (r&7).
//  lV [64][128] linear; same XOR on 16B slot index.
// Bank math: reads are 2-way per 16-lane phase = free (m136), same as the
// old 72/136-stride padding. Source pre-swizzle per rule #21.
// History: r0 cvtpk+exp2 140.9->93.3; r7 setprio 93.9->88.0 (MfmaUtil 36).
// ---------------------------------------------------------------------------
__global__ __launch_bounds__(256, 4) void attn_kernel(
    const short* __restrict__ Qh, const short* __restrict__ Kh,
    const short* __restrict__ Vt, short* __restrict__ concat) {
    const int tid  = threadIdx.x;
    const int lane = tid & 63;
    const int w    = tid >> 6;
    const int c  = lane & 31;
    const int h5 = lane >> 5;
    const int qsel = w & 1;
    const int ksel = w >> 1;
    const int bh = blockIdx.y;
    const int b = bh >> 3, h = bh & 7;
    const int qq = blockIdx.x * 64 + qsel * 32 + c;

    const short* Qp = Qh + (size_t)bh * SEQ * DKH;
    const short* Kp = Kh + (size_t)bh * SEQ * DKH;
    const short* Vp = Vt + (size_t)bh * DKH * SEQ;   // [dk][perm(s)]

    __shared__ __align__(128) char smem[33280];
    short* lK = (short*)smem;              // [128][64] swizzled
    short* lV = (short*)(smem + 16384);    // [64][128] swizzled
    float* cO = (float*)smem;              // combine area (aliased, 16 KB)
    float* cL = (float*)(smem + 32768);    // 64 floats

    const int l8 = lane >> 3, cb = lane & 7;   // K-DMA lane split
    const int sw8 = cb ^ l8;                   // K source pre-swizzle
    const int r4 = lane >> 4, cs = lane & 15;  // V-DMA lane split

    const float QS = 0.125f * 1.44269504f;
    bf16x8 qf[4];
    for (int ks = 0; ks < 4; ks++) {
        bf16x8 raw = *(const bf16x8*)&Qp[(size_t)qq * DKH + ks * 16 + h5 * 8];
        union { unsigned u[4]; bf16x8 v; } t;
        for (int j = 0; j < 4; j++)
            t.u[j] = cvtpk(b2f((unsigned short)raw[2 * j]) * QS,
                           b2f((unsigned short)raw[2 * j + 1]) * QS);
        qf[ks] = t.v;
    }

    // DMA staging: K = 4 instrs/wave (8 rows each), V = 4 instrs/wave (4 rows).
    auto stageKV = [&](int kb) {
#pragma unroll
        for (int i = 0; i < 4; i++) {
            const int rbK = w * 32 + i * 8;                 // wave-uniform
            gload_lds16(&Kp[(size_t)(kb + rbK + l8) * DKH + sw8 * 8],
                        &lK[rbK * 64]);
            const int rbV = w * 16 + i * 4;                 // wave-uniform
            const int swv = cs ^ ((rbV + r4) & 7);          // V source swizzle
            gload_lds16(&Vp[(size_t)(rbV + r4) * SEQ + kb + swv * 8],
                        &lV[rbV * 128]);
        }
    };

    float l_self = 0.f;
    f32x16 o_acc[2];
    for (int dt = 0; dt < 2; dt++)
        for (int r = 0; r < 16; r++) o_acc[dt][r] = 0.f;

    for (int kb = 0; kb < SEQ; kb += 128) {
        stageKV(kb);
        __syncthreads();   // vmcnt(0) drain

        f32x16 st[2];
        for (int kt = 0; kt < 2; kt++)
            for (int r = 0; r < 16; r++) st[kt][r] = -12.f;
        __builtin_amdgcn_s_setprio(1);
        for (int ks = 0; ks < 4; ks++)
            for (int kt = 0; kt < 2; kt++) {
                const int kr = ksel * 64 + kt * 32 + c;          // row (token)
                const int kslot = (ks * 2 + h5) ^ (c & 7);       // swizzled 16B slot
                bf16x8 kf = *(const bf16x8*)&lK[kr * 64 + kslot * 8];
                st[kt] = __builtin_amdgcn_mfma_f32_32x32x16_bf16(kf, qf[ks], st[kt], 0, 0, 0);
            }
        __builtin_amdgcn_s_setprio(0);

        for (int kt = 0; kt < 2; kt++)
            for (int r = 0; r < 16; r++) {
                float p = EXP2F(st[kt][r]);
                st[kt][r] = p;
                l_self += p;
            }

        __builtin_amdgcn_s_setprio(1);
        for (int ks2 = 0; ks2 < 4; ks2++) {
            const int kt = ks2 >> 1, ob = 8 * (ks2 & 1);
            union { unsigned u[4]; bf16x8 v; } pf;
            for (int j = 0; j < 4; j++)
                pf.u[j] = cvtpk(st[kt][ob + 2 * j], st[kt][ob + 2 * j + 1]);
            for (int dt = 0; dt < 2; dt++) {
                const int vr = dt * 32 + c;                       // row (dk)
                const int vslot = ((ksel * 4 + ks2) * 2 + h5) ^ (c & 7);
                bf16x8 vf = *(const bf16x8*)&lV[vr * 128 + vslot * 8];
                o_acc[dt] = __builtin_amdgcn_mfma_f32_32x32x16_bf16(vf, pf.v, o_acc[dt], 0, 0, 0);
            }
        }
        __builtin_amdgcn_s_setprio(0);
        __syncthreads();
    }

    const float half_l = l_self + __shfl_xor(l_self, 32);
    if (ksel == 1) {
        for (int dt = 0; dt < 2; dt++)
            for (int r = 0; r < 16; r++)
                cO[(((qsel * 2 + dt) * 16 + r) * 2 + h5) * 32 + c] = o_acc[dt][r];
        if (h5 == 0) cL[qsel * 32 + c] = half_l;
    }
    __syncthreads();
    if (ksel == 0) {
        const float l = half_l + cL[qsel * 32 + c];
        const float inv = 1.0f / l;
        short* crow = concat + ((size_t)(b * SEQ + qq)) * DMODEL + h * DKH;
        for (int dt = 0; dt < 2; dt++)
            for (int j2 = 0; j2 < 4; j2++) {
                const int r = j2 * 4;
                float o0 = (o_acc[dt][r + 0] + cO[(((qsel * 2 + dt) * 16 + r + 0) * 2 + h5) * 32 + c]) * inv;
                float o1 = (o_acc[dt][r + 1] + cO[(((qsel * 2 + dt) * 16 + r + 1) * 2 + h5) * 32 + c]) * inv;
                float o2 = (o_acc[dt][r + 2] + cO[(((qsel * 2 + dt) * 16 + r + 2) * 2 + h5) * 32 + c]) * inv;
                float o3 = (o_acc[dt][r + 3] + cO[(((qsel * 2 + dt) * 16 + r + 3) * 2 + h5) * 32 + c]) * inv;
                union { unsigned u[2]; s16x4 v; } pk;
                pk.u[0] = cvtpk(o0, o1);
                pk.u[1] = cvtpk(o2, o3);
                const int dk = dt * 32 + 8 * j2 + 4 * h5;
                *(s16x4*)&crow[dk] = pk.v;
            }
    }
}

extern "C" void kernel_launch(void* const* d_in, const int* in_sizes, int n_in,
                              void* d_out, int out_size, void* d_ws, size_t ws_size,
                              hipStream_t stream) {
    const float* q  = (const float*)d_in[0];
    const float* k  = (const float*)d_in[1];
    const float* v  = (const float*)d_in[2];
    const float* Wq = (const float*)d_in[3];
    const float* bq = (const float*)d_in[4];
    const float* Wk = (const float*)d_in[5];
    const float* bk = (const float*)d_in[6];
    const float* Wv = (const float*)d_in[7];
    const float* bv = (const float*)d_in[8];
    const float* Wo = (const float*)d_in[9];
    const float* bo = (const float*)d_in[10];

    const size_t nElemH = (size_t)BATCH * NHEAD * SEQ * DKH;  // 4,194,304
    const size_t nElemW = (size_t)DMODEL * DMODEL;            // 262,144
    short* Qh    = (short*)d_ws;
    short* Kh    = Qh + nElemH;
    short* Vt    = Kh + nElemH;
    short* bfbuf = Vt + nElemH;      // qb|kb|vb|Wqb|Wkb|Wvb|Wob contiguous
    short* qb    = bfbuf;
    short* kb    = qb + nElemH;
    short* vb    = kb + nElemH;
    short* Wqb   = vb + nElemH;
    short* Wkb   = Wqb + nElemW;
    short* Wvb   = Wkb + nElemW;
    short* Wob   = Wvb + nElemW;
    // concat aliases qb: qb is dead once qkv_kernel completes (stream-ordered
    // before attn writes concat). Saves 8 MB of ws.
    short* concat = qb;

    dim3 blk(256);
    convert_kernel<<<dim3(6656), blk, 0, stream>>>(q, k, v, Wq, Wk, Wv, Wo, bfbuf);
    qkv_kernel<<<dim3(MROWS / 128, DMODEL / 128, 3), blk, 0, stream>>>(
        qb, kb, vb, Wqb, Wkb, Wvb, bq, bk, bv, Qh, Kh, Vt);
    attn_kernel<<<dim3(SEQ / 64, BATCH * NHEAD), blk, 0, stream>>>(Qh, Kh, Vt, concat);
    oproj_kernel<<<dim3(MROWS / 64, DMODEL / 128), blk, 0, stream>>>(
        concat, Wob, bo, (float*)d_out);
}

// Round 13
// 221.873 us; speedup vs baseline: 1.0270x; 1.0270x over previous
//
#include <hip/hip_runtime.h>
#include <hip/hip_bf16.h>

#define NHEAD 8
#define DKH 64
#define DMODEL 512
#define SEQ 4096
#define BATCH 2
#define MROWS (BATCH * SEQ)  // 8192

using bf16x8 = __attribute__((ext_vector_type(8))) short;
using s16x4  = __attribute__((ext_vector_type(4))) short;
using f32x4  = __attribute__((ext_vector_type(4))) float;
using f32x16 = __attribute__((ext_vector_type(16))) float;

__device__ __forceinline__ float b2f(unsigned short u) {
    union { unsigned short u; __hip_bfloat16 h; } c; c.u = u; return __bfloat162float(c.h);
}
// round-half-up f32->bf16: 2 VALU ops, max rel err 2^-9.
__device__ __forceinline__ short rhu(float x) {
    union { float f; unsigned u; } c; c.f = x;
    return (short)((c.u + 0x8000u) >> 16);
}

// HW convert+pack: two f32 -> one dword of 2 bf16 (RNE). 1 VALU instr.
__device__ __forceinline__ unsigned cvtpk(float lo, float hi) {
    unsigned r;
    asm("v_cvt_pk_bf16_f32 %0, %1, %2" : "=v"(r) : "v"(lo), "v"(hi));
    return r;
}

// Bare v_exp_f32 (2^x). Fixed-max softmax keeps inputs in normal range.
#if __has_builtin(__builtin_amdgcn_exp2f)
#define EXP2F(x) __builtin_amdgcn_exp2f(x)
#else
#define EXP2F(x) exp2f(x)
#endif

// Direct global->LDS DMA, 16 B/lane. LDS dest must be WAVE-UNIFORM base
// (HW adds lane*16); global src is per-lane (m104/m173).
// NOTE (r10): in attn this DMA's LDS-WRITE side serialized (8 extra
// cycles/instr, 2^23 SQ_LDS_BANK_CONFLICT/dispatch) and was net-negative;
// reg-staging there was already TLP-hidden. Kept for the GEMMs, where it is
// the verified-best staging (r3 vs r1/r2 reg variants).
__device__ __forceinline__ void gload_lds16(const void* g, void* l) {
    __builtin_amdgcn_global_load_lds(
        (const __attribute__((address_space(1))) void*)g,
        (__attribute__((address_space(3))) void*)l,
        16, 0, 0);
}

// ---------------------------------------------------------------------------
// Pre-convert pass: fp32 -> bf16 for q,k,v and all four weight matrices so
// every GEMM operand stages via global_load_lds. Memory-bound (~81 MB moved,
// ~13 us = at BW ceiling). dst: qb | kb | vb | Wqb | Wkb | Wvb | Wob.
// ---------------------------------------------------------------------------
#define QG ((size_t)MROWS * DMODEL / 8)   // 524288 8-elem groups per tensor
#define WG ((size_t)DMODEL * DMODEL / 8)  // 32768 per weight

__global__ __launch_bounds__(256) void convert_kernel(
    const float* __restrict__ q, const float* __restrict__ k, const float* __restrict__ v,
    const float* __restrict__ Wq, const float* __restrict__ Wk,
    const float* __restrict__ Wv, const float* __restrict__ Wo,
    short* __restrict__ dst) {
    const size_t i = (size_t)blockIdx.x * 256 + threadIdx.x;  // 8-elem group
    const float* src;
    size_t off;
    if (i < 3 * QG) {
        size_t s = i / QG;                 // pow2 shift
        off = (i - s * QG) * 8;
        src = (s == 0) ? q : (s == 1) ? k : v;
    } else {
        size_t j = i - 3 * QG;
        size_t s = j / WG;
        off = (j - s * WG) * 8;
        src = (s == 0) ? Wq : (s == 1) ? Wk : (s == 2) ? Wv : Wo;
    }
    float4 a = *(const float4*)(src + off);
    float4 b = *(const float4*)(src + off + 4);
    union { unsigned u[4]; bf16x8 v8; } t;
    t.u[0] = cvtpk(a.x, a.y);
    t.u[1] = cvtpk(a.z, a.w);
    t.u[2] = cvtpk(b.x, b.y);
    t.u[3] = cvtpk(b.z, b.w);
    *(bf16x8*)&dst[i * 8] = t.v8;
}

// ---------------------------------------------------------------------------
// GEMM core — round-3 structure (rest = 136.4/137.3 us, twice reproduced):
// single-buffer width-16 global_load_lds into linear LDS [row][64],
// XOR-swizzled both-sides (rule #21); 2-barrier K-loop (m114 wave TLP does
// the pipelining; dbuf cost ~6 us via occupancy, m132); SCALAR epilogues,
// channel-per-lane orientation (coalesced across lanes; the swapped
// token-major wide stores cost ~11 us, r9).
// EPI 0: out[m*512+n] fp32                            [oproj]
// EPI 1: head scatter [b,h,s,dk], bf16                [Q,K proj]
// EPI 2: permuted V^T scatter [b,h,dk,perm(s)], bf16  [V proj]
// ---------------------------------------------------------------------------
template <int EPI, int TM>
__device__ __forceinline__ void gemm_core(const short* __restrict__ A,
                                          const short* __restrict__ W,
                                          const float* __restrict__ bias,
                                          void* __restrict__ out,
                                          int bm, int bn) {
    constexpr int MT = TM / 32;            // 16-row tiles per wave (m dir)
    constexpr int AI = TM / 32;            // lA DMA instrs per wave
    __shared__ __align__(128) short lA[TM * 64];
    __shared__ __align__(128) short lB[128 * 64];

    const int tid  = threadIdx.x;
    const int lane = tid & 63;
    const int w    = tid >> 6;
    const int wr = w >> 1, wc = w & 1;
    const int g = lane >> 4, ln = lane & 15;
    const int l8 = lane >> 3, cb = lane & 7;   // DMA: row-in-group, col-group
    const int sw8 = cb ^ l8;                   // pre-swizzled global k8-group

    const f32x4 zero = {0.f, 0.f, 0.f, 0.f};
    f32x4 acc[MT][4];
    for (int mt = 0; mt < MT; mt++)
        for (int nt = 0; nt < 4; nt++) acc[mt][nt] = zero;

    for (int kb = 0; kb < DMODEL; kb += 64) {
        for (int i = 0; i < AI; i++) {
            const int rb = w * (8 * AI) + i * 8;     // wave-uniform row base
            gload_lds16(&A[(size_t)(bm + rb + l8) * DMODEL + kb + sw8 * 8],
                        &lA[rb * 64]);
        }
        for (int i = 0; i < 4; i++) {
            const int rb = w * 32 + i * 8;
            gload_lds16(&W[(size_t)(bn + rb + l8) * DMODEL + kb + sw8 * 8],
                        &lB[rb * 64]);
        }
        __syncthreads();   // compiler emits vmcnt(0) drain here

        for (int ks = 0; ks < 2; ks++) {
            const int xr = (ks * 4 + g) ^ (ln & 7);  // swizzled 16B slot
            bf16x8 af[MT], bf[4];
            for (int mt = 0; mt < MT; mt++) {
                const int row = wr * 16 * MT + mt * 16 + ln;
                af[mt] = *(const bf16x8*)&lA[row * 64 + xr * 8];
            }
            for (int nt = 0; nt < 4; nt++) {
                const int row = wc * 64 + nt * 16 + ln;
                bf[nt] = *(const bf16x8*)&lB[row * 64 + xr * 8];
            }
            for (int mt = 0; mt < MT; mt++)
                for (int nt = 0; nt < 4; nt++)
                    acc[mt][nt] = __builtin_amdgcn_mfma_f32_16x16x32_bf16(
                        af[mt], bf[nt], acc[mt][nt], 0, 0, 0);
        }
        __syncthreads();
    }

    if (EPI == 2) {
        for (int mt = 0; mt < MT; mt++) {
            for (int r = 0; r < 4; r++) {
                const int m = bm + wr * 16 * MT + mt * 16 + g * 4 + r;  // channel
                const float bz = ((const float*)bias)[m];
                const int hh = m >> 6, dk = m & 63;
                for (int nt = 0; nt < 4; nt++) {
                    const int n = bn + wc * 64 + nt * 16 + ln;          // token
                    const int bb = n >> 12, s = n & 4095;
                    const int sl = s & 127, sh = s & ~127;
                    const int kt = sl >> 5, kk = sl & 31;
                    const int t = kk >> 3, hb = (kk >> 2) & 1, lo = kk & 3;
                    const int kappa = kt * 32 + (t >> 1) * 16 + hb * 8 + (t & 1) * 4 + lo;
                    ((short*)out)[(((size_t)(bb * NHEAD + hh)) * DKH + dk) * SEQ + sh + kappa] =
                        rhu(acc[mt][nt][r] + bz);
                }
            }
        }
    } else {
        for (int nt = 0; nt < 4; nt++) {
            const int n = bn + wc * 64 + nt * 16 + ln;
            const float bz = ((const float*)bias)[n];
            for (int mt = 0; mt < MT; mt++) {
                for (int r = 0; r < 4; r++) {
                    const int m = bm + wr * 16 * MT + mt * 16 + g * 4 + r;
                    const float val = acc[mt][nt][r] + bz;
                    if (EPI == 1) {
                        const int bb = m >> 12, s = m & 4095;
                        const int hh = n >> 6, dk = n & 63;
                        ((short*)out)[(((size_t)(bb * NHEAD + hh)) * SEQ + s) * DKH + dk] =
                            rhu(val);
                    } else {
                        ((float*)out)[(size_t)m * DMODEL + n] = val;
                    }
                }
            }
        }
    }
}

// Merged Q/K/V projections: z=0 Q, z=1 K (EPI1, A=data tokens on M);
// z=2 V^T (EPI2, A=weights channels on M, coords swapped).
__global__ __launch_bounds__(256) void qkv_kernel(
    const short* __restrict__ qb, const short* __restrict__ kb, const short* __restrict__ vb,
    const short* __restrict__ Wqb, const short* __restrict__ Wkb, const short* __restrict__ Wvb,
    const float* __restrict__ bq, const float* __restrict__ bk, const float* __restrict__ bv,
    short* __restrict__ Qh, short* __restrict__ Kh, short* __restrict__ Vt) {
    if (blockIdx.z == 0) {
        gemm_core<1, 128>(qb, Wqb, bq, Qh, blockIdx.x * 128, blockIdx.y * 128);
    } else if (blockIdx.z == 1) {
        gemm_core<1, 128>(kb, Wkb, bk, Kh, blockIdx.x * 128, blockIdx.y * 128);
    } else {
        // vproj operand-swapped: rows = channels (y), cols = tokens (x)
        gemm_core<2, 128>(Wvb, vb, bv, Vt, blockIdx.y * 128, blockIdx.x * 128);
    }
}

// oproj: A = concat (tokens on M, TM=64), W = Wo. 512 blocks, 24 KB LDS.
__global__ __launch_bounds__(256) void oproj_kernel(
    const short* __restrict__ A, const short* __restrict__ W,
    const float* __restrict__ bias, float* __restrict__ out) {
    gemm_core<0, 64>(A, W, bias, out, blockIdx.x * 64, blockIdx.y * 128);
}

// ---------------------------------------------------------------------------
// Flash attention — round-9 verified body (88-89 us, x4 reproductions, 0 bank
// conflicts): reg-staged K/V into padded LDS (72/136 strides), stage -> sync
// -> compute -> sync, T5 setprio around both MFMA clusters.
// Ladder: r0 cvtpk+exp2 diet 140.9 -> 93.3 (MfmaUtil 21 -> 33); r7 setprio
// 93.3 -> 88.0 (MfmaUtil 36). Quarantined-negative: r6 reg-pipelined T14
// (broke correctness), r10 DMA staging (write-side serialization, 2^23
// conflicts, +1.2 us). Staging is TLP-hidden on this structure; remaining
// headroom (MfmaUtil 36%) requires a deep-pipeline restructure whose
// isolated precursors all measured null-to-negative here.
// ---------------------------------------------------------------------------
__global__ __launch_bounds__(256, 4) void attn_kernel(
    const short* __restrict__ Qh, const short* __restrict__ Kh,
    const short* __restrict__ Vt, short* __restrict__ concat) {
    const int tid  = threadIdx.x;
    const int lane = tid & 63;
    const int w    = tid >> 6;
    const int c  = lane & 31;
    const int h5 = lane >> 5;
    const int qsel = w & 1;
    const int ksel = w >> 1;
    const int bh = blockIdx.y;
    const int b = bh >> 3, h = bh & 7;
    const int qq = blockIdx.x * 64 + qsel * 32 + c;

    const short* Qp = Qh + (size_t)bh * SEQ * DKH;
    const short* Kp = Kh + (size_t)bh * SEQ * DKH;
    const short* Vp = Vt + (size_t)bh * DKH * SEQ;   // [dk][perm(s)]

    __shared__ __align__(16) char smem[35840];
    short* lK = (short*)smem;              // [128][72]
    short* lV = (short*)(smem + 18432);    // [64][136]
    float* cO = (float*)smem;              // combine area (aliased)
    float* cL = (float*)(smem + 32768);

    const float QS = 0.125f * 1.44269504f;
    bf16x8 qf[4];
    for (int ks = 0; ks < 4; ks++) {
        bf16x8 raw = *(const bf16x8*)&Qp[(size_t)qq * DKH + ks * 16 + h5 * 8];
        union { unsigned u[4]; bf16x8 v; } t;
        for (int j = 0; j < 4; j++)
            t.u[j] = cvtpk(b2f((unsigned short)raw[2 * j]) * QS,
                           b2f((unsigned short)raw[2 * j + 1]) * QS);
        qf[ks] = t.v;
    }

    float l_self = 0.f;
    f32x16 o_acc[2];
    for (int dt = 0; dt < 2; dt++)
        for (int r = 0; r < 16; r++) o_acc[dt][r] = 0.f;

    for (int kb = 0; kb < SEQ; kb += 128) {
        for (int i = 0; i < 4; i++) {
            int vv = tid + i * 256;
            {
                int row = vv >> 3, cv = vv & 7;
                *(bf16x8*)&lK[row * 72 + cv * 8] =
                    *(const bf16x8*)&Kp[(size_t)(kb + row) * DKH + cv * 8];
            }
            {
                int dk = vv >> 4, kc = vv & 15;
                *(bf16x8*)&lV[dk * 136 + kc * 8] =
                    *(const bf16x8*)&Vp[(size_t)dk * SEQ + kb + kc * 8];
            }
        }
        __syncthreads();

        f32x16 st[2];
        for (int kt = 0; kt < 2; kt++)
            for (int r = 0; r < 16; r++) st[kt][r] = -12.f;
        __builtin_amdgcn_s_setprio(1);
        for (int ks = 0; ks < 4; ks++)
            for (int kt = 0; kt < 2; kt++) {
                bf16x8 kf = *(const bf16x8*)&lK[(ksel * 64 + kt * 32 + c) * 72 + ks * 16 + h5 * 8];
                st[kt] = __builtin_amdgcn_mfma_f32_32x32x16_bf16(kf, qf[ks], st[kt], 0, 0, 0);
            }
        __builtin_amdgcn_s_setprio(0);

        for (int kt = 0; kt < 2; kt++)
            for (int r = 0; r < 16; r++) {
                float p = EXP2F(st[kt][r]);
                st[kt][r] = p;
                l_self += p;
            }

        __builtin_amdgcn_s_setprio(1);
        for (int ks2 = 0; ks2 < 4; ks2++) {
            const int kt = ks2 >> 1, ob = 8 * (ks2 & 1);
            union { unsigned u[4]; bf16x8 v; } pf;
            for (int j = 0; j < 4; j++)
                pf.u[j] = cvtpk(st[kt][ob + 2 * j], st[kt][ob + 2 * j + 1]);
            const int colg = (ksel * 4 + ks2) * 16 + h5 * 8;
            for (int dt = 0; dt < 2; dt++) {
                bf16x8 vf = *(const bf16x8*)&lV[(dt * 32 + c) * 136 + colg];
                o_acc[dt] = __builtin_amdgcn_mfma_f32_32x32x16_bf16(vf, pf.v, o_acc[dt], 0, 0, 0);
            }
        }
        __builtin_amdgcn_s_setprio(0);
        __syncthreads();
    }

    const float half_l = l_self + __shfl_xor(l_self, 32);
    if (ksel == 1) {
        for (int dt = 0; dt < 2; dt++)
            for (int r = 0; r < 16; r++)
                cO[(((qsel * 2 + dt) * 16 + r) * 2 + h5) * 32 + c] = o_acc[dt][r];
        if (h5 == 0) cL[qsel * 32 + c] = half_l;
    }
    __syncthreads();
    if (ksel == 0) {
        const float l = half_l + cL[qsel * 32 + c];
        const float inv = 1.0f / l;
        short* crow = concat + ((size_t)(b * SEQ + qq)) * DMODEL + h * DKH;
        for (int dt = 0; dt < 2; dt++)
            for (int j2 = 0; j2 < 4; j2++) {
                const int r = j2 * 4;
                float o0 = (o_acc[dt][r + 0] + cO[(((qsel * 2 + dt) * 16 + r + 0) * 2 + h5) * 32 + c]) * inv;
                float o1 = (o_acc[dt][r + 1] + cO[(((qsel * 2 + dt) * 16 + r + 1) * 2 + h5) * 32 + c]) * inv;
                float o2 = (o_acc[dt][r + 2] + cO[(((qsel * 2 + dt) * 16 + r + 2) * 2 + h5) * 32 + c]) * inv;
                float o3 = (o_acc[dt][r + 3] + cO[(((qsel * 2 + dt) * 16 + r + 3) * 2 + h5) * 32 + c]) * inv;
                union { unsigned u[2]; s16x4 v; } pk;
                pk.u[0] = cvtpk(o0, o1);
                pk.u[1] = cvtpk(o2, o3);
                const int dk = dt * 32 + 8 * j2 + 4 * h5;
                *(s16x4*)&crow[dk] = pk.v;
            }
    }
}

extern "C" void kernel_launch(void* const* d_in, const int* in_sizes, int n_in,
                              void* d_out, int out_size, void* d_ws, size_t ws_size,
                              hipStream_t stream) {
    const float* q  = (const float*)d_in[0];
    const float* k  = (const float*)d_in[1];
    const float* v  = (const float*)d_in[2];
    const float* Wq = (const float*)d_in[3];
    const float* bq = (const float*)d_in[4];
    const float* Wk = (const float*)d_in[5];
    const float* bk = (const float*)d_in[6];
    const float* Wv = (const float*)d_in[7];
    const float* bv = (const float*)d_in[8];
    const float* Wo = (const float*)d_in[9];
    const float* bo = (const float*)d_in[10];

    const size_t nElemH = (size_t)BATCH * NHEAD * SEQ * DKH;  // 4,194,304
    const size_t nElemW = (size_t)DMODEL * DMODEL;            // 262,144
    short* Qh    = (short*)d_ws;
    short* Kh    = Qh + nElemH;
    short* Vt    = Kh + nElemH;
    short* bfbuf = Vt + nElemH;      // qb|kb|vb|Wqb|Wkb|Wvb|Wob contiguous
    short* qb    = bfbuf;
    short* kb    = qb + nElemH;
    short* vb    = kb + nElemH;
    short* Wqb   = vb + nElemH;
    short* Wkb   = Wqb + nElemW;
    short* Wvb   = Wkb + nElemW;
    short* Wob   = Wvb + nElemW;
    // concat aliases qb: qb is dead once qkv_kernel completes (stream-ordered
    // before attn writes concat). Saves 8 MB of ws.
    short* concat = qb;

    dim3 blk(256);
    convert_kernel<<<dim3(6656), blk, 0, stream>>>(q, k, v, Wq, Wk, Wv, Wo, bfbuf);
    qkv_kernel<<<dim3(MROWS / 128, DMODEL / 128, 3), blk, 0, stream>>>(
        qb, kb, vb, Wqb, Wkb, Wvb, bq, bk, bv, Qh, Kh, Vt);
    attn_kernel<<<dim3(SEQ / 64, BATCH * NHEAD), blk, 0, stream>>>(Qh, Kh, Vt, concat);
    oproj_kernel<<<dim3(MROWS / 64, DMODEL / 128), blk, 0, stream>>>(
        concat, Wob, bo, (float*)d_out);
}

// Round 14
// 221.467 us; speedup vs baseline: 1.0289x; 1.0018x over previous
//
#include <hip/hip_runtime.h>
#include <hip/hip_bf16.h>

#define NHEAD 8
#define DKH 64
#define DMODEL 512
#define SEQ 4096
#define BATCH 2
#define MROWS (BATCH * SEQ)  // 8192

using bf16x8 = __attribute__((ext_vector_type(8))) short;
using s16x4  = __attribute__((ext_vector_type(4))) short;
using f32x4  = __attribute__((ext_vector_type(4))) float;
using f32x16 = __attribute__((ext_vector_type(16))) float;

__device__ __forceinline__ float b2f(unsigned short u) {
    union { unsigned short u; __hip_bfloat16 h; } c; c.u = u; return __bfloat162float(c.h);
}
// round-half-up f32->bf16: 2 VALU ops, max rel err 2^-9.
__device__ __forceinline__ short rhu(float x) {
    union { float f; unsigned u; } c; c.f = x;
    return (short)((c.u + 0x8000u) >> 16);
}

// HW convert+pack: two f32 -> one dword of 2 bf16 (RNE). 1 VALU instr.
__device__ __forceinline__ unsigned cvtpk(float lo, float hi) {
    unsigned r;
    asm("v_cvt_pk_bf16_f32 %0, %1, %2" : "=v"(r) : "v"(lo), "v"(hi));
    return r;
}

// Bare v_exp_f32 (2^x). Fixed-max softmax keeps inputs in normal range.
#if __has_builtin(__builtin_amdgcn_exp2f)
#define EXP2F(x) __builtin_amdgcn_exp2f(x)
#else
#define EXP2F(x) exp2f(x)
#endif

// Direct global->LDS DMA, 16 B/lane. LDS dest must be WAVE-UNIFORM base
// (HW adds lane*16); global src is per-lane (m104/m173).
// r10 NOTE: in attn this DMA's LDS-write side serialized (2^23 conflicts);
// kept only where verified-best (GEMM weight/bf16 operands).
__device__ __forceinline__ void gload_lds16(const void* g, void* l) {
    __builtin_amdgcn_global_load_lds(
        (const __attribute__((address_space(1))) void*)g,
        (__attribute__((address_space(3))) void*)l,
        16, 0, 0);
}

// ---------------------------------------------------------------------------
// Pre-convert pass — WEIGHTS ONLY (round 14): fp32 -> bf16 for Wq/Wk/Wv/Wo
// (4 MB, ~1-2 us). Data tensors q,k,v are now inline-converted during qkv
// staging (r1/r2 proved staging-conversion VALU is off the critical path;
// this deletes ~12 us of convert + 24 MB of ws round-trip).
// dst: Wqb | Wkb | Wvb | Wob.
// ---------------------------------------------------------------------------
#define WG ((size_t)DMODEL * DMODEL / 8)  // 32768 8-elem groups per weight

__global__ __launch_bounds__(256) void convert_kernel(
    const float* __restrict__ Wq, const float* __restrict__ Wk,
    const float* __restrict__ Wv, const float* __restrict__ Wo,
    short* __restrict__ dst) {
    const size_t i = (size_t)blockIdx.x * 256 + threadIdx.x;  // 8-elem group
    const size_t s = i / WG;
    const size_t off = (i - s * WG) * 8;
    const float* src = (s == 0) ? Wq : (s == 1) ? Wk : (s == 2) ? Wv : Wo;
    float4 a = *(const float4*)(src + off);
    float4 b = *(const float4*)(src + off + 4);
    union { unsigned u[4]; bf16x8 v8; } t;
    t.u[0] = cvtpk(a.x, a.y);
    t.u[1] = cvtpk(a.z, a.w);
    t.u[2] = cvtpk(b.x, b.y);
    t.u[3] = cvtpk(b.z, b.w);
    *(bf16x8*)&dst[i * 8] = t.v8;
}

// Staging register block for one bf16x8 LDS slot (r2-verified path).
template <bool F32>
struct St8 {
    float4 a, b;   // F32 form
    bf16x8 d;      // direct bf16 form
    __device__ __forceinline__ void load(const void* p, size_t eidx) {
        if constexpr (F32) {
            const float* f = (const float*)p + eidx;
            a = *(const float4*)f;
            b = *(const float4*)(f + 4);
        } else {
            d = *(const bf16x8*)((const short*)p + eidx);
        }
    }
    __device__ __forceinline__ bf16x8 pack() const {
        if constexpr (F32) {
            union { unsigned u[4]; bf16x8 v; } t;
            t.u[0] = cvtpk(a.x, a.y);
            t.u[1] = cvtpk(a.z, a.w);
            t.u[2] = cvtpk(b.x, b.y);
            t.u[3] = cvtpk(b.z, b.w);
            return t.v;
        } else {
            return d;
        }
    }
};

// ---------------------------------------------------------------------------
// GEMM core — r3 K-loop structure (rest reproduced 135-137 us), now with
// per-operand staging mode:
//  * bf16 operands: width-16 global_load_lds, pre-swizzled global source
//    (verified-best, r3).
//  * fp32 operands (raw q/k/v): r2-style reg-stage (load fp32 -> cvtpk ->
//    ds_write at SWIZZLED slot). Write-swz + read-swz = same involution
//    (rule #21): slot x of row r holds logical k8 = x ^ (r&7).
// Both land in identical LDS layout; compute/read side unchanged.
// 2-barrier K-loop (wave TLP pipelines, m114; dbuf cost ~6 us, r4).
// SCALAR epilogues, channel-per-lane (coalesced; r9's swap cost ~11 us).
// EPI 0: out[m*512+n] fp32                            [oproj]
// EPI 1: head scatter [b,h,s,dk], bf16                [Q,K proj]
// EPI 2: permuted V^T scatter [b,h,dk,perm(s)], bf16  [V proj]
// ---------------------------------------------------------------------------
template <int EPI, int TM, bool F32A, bool F32W>
__device__ __forceinline__ void gemm_core(const void* __restrict__ A,
                                          const void* __restrict__ W,
                                          const float* __restrict__ bias,
                                          void* __restrict__ out,
                                          int bm, int bn) {
    constexpr int MT = TM / 32;            // 16-row tiles per wave (m dir)
    constexpr int AI = TM / 32;            // lA staging iters
    __shared__ __align__(128) short lA[TM * 64];
    __shared__ __align__(128) short lB[128 * 64];

    const int tid  = threadIdx.x;
    const int lane = tid & 63;
    const int w    = tid >> 6;
    const int wr = w >> 1, wc = w & 1;
    const int g = lane >> 4, ln = lane & 15;
    const int l8 = lane >> 3, cb = lane & 7;   // DMA: row-in-group, col-group
    const int sw8 = cb ^ l8;                   // pre-swizzled global k8-group

    const f32x4 zero = {0.f, 0.f, 0.f, 0.f};
    f32x4 acc[MT][4];
    for (int mt = 0; mt < MT; mt++)
        for (int nt = 0; nt < 4; nt++) acc[mt][nt] = zero;

    for (int kb = 0; kb < DMODEL; kb += 64) {
        if constexpr (F32A) {
            for (int i = 0; i < AI; i++) {
                const int vv = tid + i * 256;
                const int row = vv >> 3, cv = vv & 7;
                St8<true> s;
                s.load(A, (size_t)(bm + row) * DMODEL + kb + cv * 8);
                *(bf16x8*)&lA[row * 64 + (cv ^ (row & 7)) * 8] = s.pack();
            }
        } else {
            for (int i = 0; i < AI; i++) {
                const int rb = w * (8 * AI) + i * 8;   // wave-uniform row base
                gload_lds16(&((const short*)A)[(size_t)(bm + rb + l8) * DMODEL + kb + sw8 * 8],
                            &lA[rb * 64]);
            }
        }
        if constexpr (F32W) {
            for (int i = 0; i < 4; i++) {
                const int vv = tid + i * 256;
                const int row = vv >> 3, cv = vv & 7;
                St8<true> s;
                s.load(W, (size_t)(bn + row) * DMODEL + kb + cv * 8);
                *(bf16x8*)&lB[row * 64 + (cv ^ (row & 7)) * 8] = s.pack();
            }
        } else {
            for (int i = 0; i < 4; i++) {
                const int rb = w * 32 + i * 8;
                gload_lds16(&((const short*)W)[(size_t)(bn + rb + l8) * DMODEL + kb + sw8 * 8],
                            &lB[rb * 64]);
            }
        }
        __syncthreads();   // drains vmcnt (DMA) and lgkm (ds_write)

        for (int ks = 0; ks < 2; ks++) {
            const int xr = (ks * 4 + g) ^ (ln & 7);  // swizzled 16B slot
            bf16x8 af[MT], bf[4];
            for (int mt = 0; mt < MT; mt++) {
                const int row = wr * 16 * MT + mt * 16 + ln;
                af[mt] = *(const bf16x8*)&lA[row * 64 + xr * 8];
            }
            for (int nt = 0; nt < 4; nt++) {
                const int row = wc * 64 + nt * 16 + ln;
                bf[nt] = *(const bf16x8*)&lB[row * 64 + xr * 8];
            }
            for (int mt = 0; mt < MT; mt++)
                for (int nt = 0; nt < 4; nt++)
                    acc[mt][nt] = __builtin_amdgcn_mfma_f32_16x16x32_bf16(
                        af[mt], bf[nt], acc[mt][nt], 0, 0, 0);
        }
        __syncthreads();
    }

    if (EPI == 2) {
        for (int mt = 0; mt < MT; mt++) {
            for (int r = 0; r < 4; r++) {
                const int m = bm + wr * 16 * MT + mt * 16 + g * 4 + r;  // channel
                const float bz = bias[m];
                const int hh = m >> 6, dk = m & 63;
                for (int nt = 0; nt < 4; nt++) {
                    const int n = bn + wc * 64 + nt * 16 + ln;          // token
                    const int bb = n >> 12, s = n & 4095;
                    const int sl = s & 127, sh = s & ~127;
                    const int kt = sl >> 5, kk = sl & 31;
                    const int t = kk >> 3, hb = (kk >> 2) & 1, lo = kk & 3;
                    const int kappa = kt * 32 + (t >> 1) * 16 + hb * 8 + (t & 1) * 4 + lo;
                    ((short*)out)[(((size_t)(bb * NHEAD + hh)) * DKH + dk) * SEQ + sh + kappa] =
                        rhu(acc[mt][nt][r] + bz);
                }
            }
        }
    } else {
        for (int nt = 0; nt < 4; nt++) {
            const int n = bn + wc * 64 + nt * 16 + ln;
            const float bz = bias[n];
            for (int mt = 0; mt < MT; mt++) {
                for (int r = 0; r < 4; r++) {
                    const int m = bm + wr * 16 * MT + mt * 16 + g * 4 + r;
                    const float val = acc[mt][nt][r] + bz;
                    if (EPI == 1) {
                        const int bb = m >> 12, s = m & 4095;
                        const int hh = n >> 6, dk = n & 63;
                        ((short*)out)[(((size_t)(bb * NHEAD + hh)) * SEQ + s) * DKH + dk] =
                            rhu(val);
                    } else {
                        ((float*)out)[(size_t)m * DMODEL + n] = val;
                    }
                }
            }
        }
    }
}

// Merged Q/K/V projections: z=0 Q, z=1 K (EPI1, A=raw fp32 data tokens on M,
// W=bf16 weights via DMA); z=2 V^T (EPI2, A=bf16 weights via DMA, W-slot=raw
// fp32 data tokens on N, coords swapped).
__global__ __launch_bounds__(256) void qkv_kernel(
    const float* __restrict__ q, const float* __restrict__ k, const float* __restrict__ v,
    const short* __restrict__ Wqb, const short* __restrict__ Wkb, const short* __restrict__ Wvb,
    const float* __restrict__ bq, const float* __restrict__ bk, const float* __restrict__ bv,
    short* __restrict__ Qh, short* __restrict__ Kh, short* __restrict__ Vt) {
    if (blockIdx.z == 0) {
        gemm_core<1, 128, true, false>(q, Wqb, bq, Qh, blockIdx.x * 128, blockIdx.y * 128);
    } else if (blockIdx.z == 1) {
        gemm_core<1, 128, true, false>(k, Wkb, bk, Kh, blockIdx.x * 128, blockIdx.y * 128);
    } else {
        // vproj operand-swapped: rows = channels (y), cols = tokens (x)
        gemm_core<2, 128, false, true>(Wvb, v, bv, Vt, blockIdx.y * 128, blockIdx.x * 128);
    }
}

// oproj: A = concat (bf16 tokens on M, TM=64), W = Wo bf16. 512 blocks.
__global__ __launch_bounds__(256) void oproj_kernel(
    const short* __restrict__ A, const short* __restrict__ W,
    const float* __restrict__ bias, float* __restrict__ out) {
    gemm_core<0, 64, false, false>(A, W, bias, out, blockIdx.x * 64, blockIdx.y * 128);
}

// ---------------------------------------------------------------------------
// Flash attention — round-9 verified body (87-89 us, x6 reproductions, 0 bank
// conflicts): reg-staged K/V into padded LDS (72/136 strides), stage -> sync
// -> compute -> sync, T5 setprio around both MFMA clusters.
// Ladder: r0 cvtpk+exp2 diet 140.9 -> 93.3 (MfmaUtil 21 -> 33); r7 setprio
// -> 88 (MfmaUtil 36). Quarantined-negative: r6 reg-pipelined T14 (broke
// correctness), r10 DMA staging (write-side serialization, 2^23 conflicts).
// ---------------------------------------------------------------------------
__global__ __launch_bounds__(256, 4) void attn_kernel(
    const short* __restrict__ Qh, const short* __restrict__ Kh,
    const short* __restrict__ Vt, short* __restrict__ concat) {
    const int tid  = threadIdx.x;
    const int lane = tid & 63;
    const int w    = tid >> 6;
    const int c  = lane & 31;
    const int h5 = lane >> 5;
    const int qsel = w & 1;
    const int ksel = w >> 1;
    const int bh = blockIdx.y;
    const int b = bh >> 3, h = bh & 7;
    const int qq = blockIdx.x * 64 + qsel * 32 + c;

    const short* Qp = Qh + (size_t)bh * SEQ * DKH;
    const short* Kp = Kh + (size_t)bh * SEQ * DKH;
    const short* Vp = Vt + (size_t)bh * DKH * SEQ;   // [dk][perm(s)]

    __shared__ __align__(16) char smem[35840];
    short* lK = (short*)smem;              // [128][72]
    short* lV = (short*)(smem + 18432);    // [64][136]
    float* cO = (float*)smem;              // combine area (aliased)
    float* cL = (float*)(smem + 32768);

    const float QS = 0.125f * 1.44269504f;
    bf16x8 qf[4];
    for (int ks = 0; ks < 4; ks++) {
        bf16x8 raw = *(const bf16x8*)&Qp[(size_t)qq * DKH + ks * 16 + h5 * 8];
        union { unsigned u[4]; bf16x8 v; } t;
        for (int j = 0; j < 4; j++)
            t.u[j] = cvtpk(b2f((unsigned short)raw[2 * j]) * QS,
                           b2f((unsigned short)raw[2 * j + 1]) * QS);
        qf[ks] = t.v;
    }

    float l_self = 0.f;
    f32x16 o_acc[2];
    for (int dt = 0; dt < 2; dt++)
        for (int r = 0; r < 16; r++) o_acc[dt][r] = 0.f;

    for (int kb = 0; kb < SEQ; kb += 128) {
        for (int i = 0; i < 4; i++) {
            int vv = tid + i * 256;
            {
                int row = vv >> 3, cv = vv & 7;
                *(bf16x8*)&lK[row * 72 + cv * 8] =
                    *(const bf16x8*)&Kp[(size_t)(kb + row) * DKH + cv * 8];
            }
            {
                int dk = vv >> 4, kc = vv & 15;
                *(bf16x8*)&lV[dk * 136 + kc * 8] =
                    *(const bf16x8*)&Vp[(size_t)dk * SEQ + kb + kc * 8];
            }
        }
        __syncthreads();

        f32x16 st[2];
        for (int kt = 0; kt < 2; kt++)
            for (int r = 0; r < 16; r++) st[kt][r] = -12.f;
        __builtin_amdgcn_s_setprio(1);
        for (int ks = 0; ks < 4; ks++)
            for (int kt = 0; kt < 2; kt++) {
                bf16x8 kf = *(const bf16x8*)&lK[(ksel * 64 + kt * 32 + c) * 72 + ks * 16 + h5 * 8];
                st[kt] = __builtin_amdgcn_mfma_f32_32x32x16_bf16(kf, qf[ks], st[kt], 0, 0, 0);
            }
        __builtin_amdgcn_s_setprio(0);

        for (int kt = 0; kt < 2; kt++)
            for (int r = 0; r < 16; r++) {
                float p = EXP2F(st[kt][r]);
                st[kt][r] = p;
                l_self += p;
            }

        __builtin_amdgcn_s_setprio(1);
        for (int ks2 = 0; ks2 < 4; ks2++) {
            const int kt = ks2 >> 1, ob = 8 * (ks2 & 1);
            union { unsigned u[4]; bf16x8 v; } pf;
            for (int j = 0; j < 4; j++)
                pf.u[j] = cvtpk(st[kt][ob + 2 * j], st[kt][ob + 2 * j + 1]);
            const int colg = (ksel * 4 + ks2) * 16 + h5 * 8;
            for (int dt = 0; dt < 2; dt++) {
                bf16x8 vf = *(const bf16x8*)&lV[(dt * 32 + c) * 136 + colg];
                o_acc[dt] = __builtin_amdgcn_mfma_f32_32x32x16_bf16(vf, pf.v, o_acc[dt], 0, 0, 0);
            }
        }
        __builtin_amdgcn_s_setprio(0);
        __syncthreads();
    }

    const float half_l = l_self + __shfl_xor(l_self, 32);
    if (ksel == 1) {
        for (int dt = 0; dt < 2; dt++)
            for (int r = 0; r < 16; r++)
                cO[(((qsel * 2 + dt) * 16 + r) * 2 + h5) * 32 + c] = o_acc[dt][r];
        if (h5 == 0) cL[qsel * 32 + c] = half_l;
    }
    __syncthreads();
    if (ksel == 0) {
        const float l = half_l + cL[qsel * 32 + c];
        const float inv = 1.0f / l;
        short* crow = concat + ((size_t)(b * SEQ + qq)) * DMODEL + h * DKH;
        for (int dt = 0; dt < 2; dt++)
            for (int j2 = 0; j2 < 4; j2++) {
                const int r = j2 * 4;
                float o0 = (o_acc[dt][r + 0] + cO[(((qsel * 2 + dt) * 16 + r + 0) * 2 + h5) * 32 + c]) * inv;
                float o1 = (o_acc[dt][r + 1] + cO[(((qsel * 2 + dt) * 16 + r + 1) * 2 + h5) * 32 + c]) * inv;
                float o2 = (o_acc[dt][r + 2] + cO[(((qsel * 2 + dt) * 16 + r + 2) * 2 + h5) * 32 + c]) * inv;
                float o3 = (o_acc[dt][r + 3] + cO[(((qsel * 2 + dt) * 16 + r + 3) * 2 + h5) * 32 + c]) * inv;
                union { unsigned u[2]; s16x4 v; } pk;
                pk.u[0] = cvtpk(o0, o1);
                pk.u[1] = cvtpk(o2, o3);
                const int dk = dt * 32 + 8 * j2 + 4 * h5;
                *(s16x4*)&crow[dk] = pk.v;
            }
    }
}

extern "C" void kernel_launch(void* const* d_in, const int* in_sizes, int n_in,
                              void* d_out, int out_size, void* d_ws, size_t ws_size,
                              hipStream_t stream) {
    const float* q  = (const float*)d_in[0];
    const float* k  = (const float*)d_in[1];
    const float* v  = (const float*)d_in[2];
    const float* Wq = (const float*)d_in[3];
    const float* bq = (const float*)d_in[4];
    const float* Wk = (const float*)d_in[5];
    const float* bk = (const float*)d_in[6];
    const float* Wv = (const float*)d_in[7];
    const float* bv = (const float*)d_in[8];
    const float* Wo = (const float*)d_in[9];
    const float* bo = (const float*)d_in[10];

    const size_t nElemH = (size_t)BATCH * NHEAD * SEQ * DKH;  // 4,194,304
    const size_t nElemW = (size_t)DMODEL * DMODEL;            // 262,144
    short* Qh    = (short*)d_ws;
    short* Kh    = Qh + nElemH;
    short* Vt    = Kh + nElemH;
    short* Wqb   = Vt + nElemH;      // Wqb|Wkb|Wvb|Wob contiguous
    short* Wkb   = Wqb + nElemW;
    short* Wvb   = Wkb + nElemW;
    short* Wob   = Wvb + nElemW;
    short* concat = Wob + nElemW;

    dim3 blk(256);
    convert_kernel<<<dim3(512), blk, 0, stream>>>(Wq, Wk, Wv, Wo, Wqb);
    qkv_kernel<<<dim3(MROWS / 128, DMODEL / 128, 3), blk, 0, stream>>>(
        q, k, v, Wqb, Wkb, Wvb, bq, bk, bv, Qh, Kh, Vt);
    attn_kernel<<<dim3(SEQ / 64, BATCH * NHEAD), blk, 0, stream>>>(Qh, Kh, Vt, concat);
    oproj_kernel<<<dim3(MROWS / 64, DMODEL / 128), blk, 0, stream>>>(
        concat, Wob, bo, (float*)d_out);
}